// Round 3
// baseline (1136.074 us; speedup 1.0000x reference)
//
#include <hip/hip_runtime.h>
#include <hip/hip_bf16.h>

// ---------------------------------------------------------------------------
// LinearSystem: chunked parallel scan (128 chunks x 8 steps), bf16 MFMA.
// Round 3: m97-class GEMM (128x128 / 64x256 tiles, global_load_lds width-16
// staging for bf16 operands, reg-staged f32->bf16 path), prefix-only KS copy.
// ---------------------------------------------------------------------------

typedef short bfrag __attribute__((ext_vector_type(8)));   // 8 x bf16 bits
typedef float f32x4 __attribute__((ext_vector_type(4)));

__device__ __host__ inline unsigned short f2bf(float f) {
    union { float f; unsigned u; } x; x.f = f;
    unsigned r = x.u + 0x7fffu + ((x.u >> 16) & 1u);   // RNE
    return (unsigned short)(r >> 16);
}
__device__ inline float bf2f(unsigned short h) {
    union { unsigned u; float f; } x; x.u = ((unsigned)h) << 16;
    return x.f;
}

__device__ inline void gload16(const void* g, void* l) {
    __builtin_amdgcn_global_load_lds(
        (__attribute__((address_space(1))) void*)g,
        (__attribute__((address_space(3))) void*)l, 16, 0, 0);
}

struct GemmDesc {
    const void* a0; const void* a1;          // A sources (k < ksplit -> a0)
    const unsigned short* b;                 // B, bf16, (N,K) row-major (B^T form)
    float* c;                                // f32 C out (nullable)
    const float* cbeta;                      // f32 beta source (beta==1)
    unsigned short* cm;                      // bf16 mirror out (nullable)
    unsigned short* cmT;                     // bf16 transposed mirror (512x512)
    long a0_base, a0_os, a0_is, a0_ic;       // row map: (r/ic)*os + (r%ic)*is
    long a1_base, a1_os, a1_is, a1_ic;
    long a_zq, a_zr;                         // z offs: (z/zdiv)*zq + (z%zdiv)*zr
    long b_base, b_ldb, b_zq, b_zr;
    long c_base, c_os, c_is, c_ic, c_zq, c_zr;
    long cm_base, cmT_base;
    long zdiv;
    int a0_f32, a1_f32, ksplit, K, beta;     // beta: 0 none, 1 f32 cbeta, 2 bf16 cm
};

template<int BM, int BN>
__global__ __launch_bounds__(256) void gemm_k(GemmDesc d) {
    constexpr int AISS = BM / 32;            // global_load_lds issues for A
    constexpr int BISS = BN / 32;
    constexpr int EPF  = BM / 4;             // f32-path elems per thread (32|16)
    constexpr int TPR  = 64 / EPF;           // f32-path threads per row (2|4)
    __shared__ __align__(16) unsigned short As[BM * 64];
    __shared__ __align__(16) unsigned short Bs[BN * 64];

    const int tid  = threadIdx.x;
    const int lane = tid & 63;
    const int w    = tid >> 6;
    const int wrow = (BM == 128) ? (w >> 1) * 64 : 0;
    const int wcol = (BM == 128) ? (w & 1) * 64 : w * 64;
    const long z  = blockIdx.z;
    const long zq = z / d.zdiv, zr = z % d.zdiv;
    const int row0 = blockIdx.y * BM;
    const int col0 = blockIdx.x * BN;

    // gload staging coords: issue i covers rows i*32 + (tid>>3), k (tid&7)*8
    const int g_r = tid >> 3;
    const int g_k = (tid & 7) * 8;
    const long za = zq * d.a_zq + zr * d.a_zr;

    long a0off[AISS], a1off[AISS];
#pragma unroll
    for (int i = 0; i < AISS; ++i) {
        const long ar = row0 + i * 32 + g_r;
        a0off[i] = d.a0_base + za + (ar / d.a0_ic) * d.a0_os + (ar % d.a0_ic) * d.a0_is;
        a1off[i] = d.a1 ? (d.a1_base + za + (ar / d.a1_ic) * d.a1_os + (ar % d.a1_ic) * d.a1_is) : 0;
    }
    long boff[BISS];
    const long zb = zq * d.b_zq + zr * d.b_zr;
#pragma unroll
    for (int i = 0; i < BISS; ++i)
        boff[i] = d.b_base + zb + (long)(col0 + i * 32 + g_r) * d.b_ldb;

    // f32 staging coords: thread covers row f_r, k [f_k, f_k+EPF)
    const int f_r = tid / TPR;
    const int f_k = (tid % TPR) * EPF;
    long af0 = 0, af1 = 0;
    {
        const long ar = row0 + f_r;
        af0 = d.a0_base + za + (ar / d.a0_ic) * d.a0_os + (ar % d.a0_ic) * d.a0_is;
        if (d.a1) af1 = d.a1_base + za + (ar / d.a1_ic) * d.a1_os + (ar % d.a1_ic) * d.a1_is;
    }

    f32x4 acc[4][4] = {};

    for (int k0 = 0; k0 < d.K; k0 += 64) {
        __syncthreads();
        const bool s1 = (k0 >= d.ksplit);
        const int kl = s1 ? (k0 - d.ksplit) : k0;
        // ---- stage A ----
        if (s1 ? d.a1_f32 : d.a0_f32) {
            const float* src = (const float*)(s1 ? d.a1 : d.a0);
            const long ro = (s1 ? af1 : af0) + kl + f_k;
            union { bfrag v[EPF / 8]; unsigned short h[EPF]; } t;
#pragma unroll
            for (int q = 0; q < EPF / 4; ++q) {
                f32x4 x = *(const f32x4*)(src + ro + q * 4);
                t.h[q * 4 + 0] = f2bf(x[0]); t.h[q * 4 + 1] = f2bf(x[1]);
                t.h[q * 4 + 2] = f2bf(x[2]); t.h[q * 4 + 3] = f2bf(x[3]);
            }
#pragma unroll
            for (int q = 0; q < EPF / 8; ++q)
                *(bfrag*)&As[f_r * 64 + f_k + q * 8] = t.v[q];
        } else {
            const unsigned short* src = (const unsigned short*)(s1 ? d.a1 : d.a0);
#pragma unroll
            for (int i = 0; i < AISS; ++i)
                gload16(src + (s1 ? a1off[i] : a0off[i]) + kl + g_k,
                        &As[i * 2048 + w * 512]);
        }
        // ---- stage B (always bf16) ----
#pragma unroll
        for (int i = 0; i < BISS; ++i)
            gload16(d.b + boff[i] + k0 + g_k, &Bs[i * 2048 + w * 512]);
        __syncthreads();
        // ---- compute: 2 k-slices x 4x4 frags ----
#pragma unroll
        for (int ks = 0; ks < 2; ++ks) {
            const int kk = ks * 32 + (lane >> 4) * 8;
            bfrag af[4], bfr[4];
#pragma unroll
            for (int mt = 0; mt < 4; ++mt)
                af[mt] = *(const bfrag*)&As[(wrow + mt * 16 + (lane & 15)) * 64 + kk];
#pragma unroll
            for (int nt = 0; nt < 4; ++nt)
                bfr[nt] = *(const bfrag*)&Bs[(wcol + nt * 16 + (lane & 15)) * 64 + kk];
#pragma unroll
            for (int mt = 0; mt < 4; ++mt)
#pragma unroll
                for (int nt = 0; nt < 4; ++nt)
                    acc[mt][nt] = __builtin_amdgcn_mfma_f32_16x16x32_bf16(
                        af[mt], bfr[nt], acc[mt][nt], 0, 0, 0);
        }
    }
    // ---- epilogue: C/D layout col=lane&15, row=(lane>>4)*4+j ----
    const long zc = zq * d.c_zq + zr * d.c_zr;
#pragma unroll
    for (int mt = 0; mt < 4; ++mt) {
        const int rb = row0 + wrow + mt * 16 + ((lane >> 4) << 2);
#pragma unroll
        for (int nt = 0; nt < 4; ++nt) {
            const int cc = col0 + wcol + nt * 16 + (lane & 15);
#pragma unroll
            for (int j = 0; j < 4; ++j) {
                const long r = rb + j;
                const long off = zc + (r / d.c_ic) * d.c_os + (r % d.c_ic) * d.c_is + cc;
                float v = acc[mt][nt][j];
                if (d.beta == 1) v += d.cbeta[d.c_base + off];
                if (d.beta == 2) v += bf2f(d.cm[d.cm_base + off]);
                if (d.c)  d.c[d.c_base + off] = v;
                if (d.cm) d.cm[d.cm_base + off] = f2bf(v);
                if (d.cmT) d.cmT[d.cmT_base + zc + (long)cc * 512 + r] = f2bf(v);
            }
        }
    }
}

// Build bf16 operators: BopD (512x768)=[B_mat|sqrt_S_W], BopO (256x768)=[H|sqrt_S_V],
// G[0]=F, Gt[0]=F^T.
__global__ void build_ops_k(const float* F, const float* Bm, const float* H,
                            const float* sW, const float* sV,
                            unsigned short* bopd, unsigned short* bopo,
                            unsigned short* G1, unsigned short* Gt1) {
    int i = blockIdx.x * 256 + threadIdx.x;
    const int n1 = 512 * 768, n2 = 256 * 768, n3 = 512 * 512;
    if (i < n1) { int n = i / 768, k = i % 768;
        bopd[i] = f2bf(k < 256 ? Bm[n * 256 + k] : sW[n * 512 + (k - 256)]); return; }
    i -= n1;
    if (i < n2) { int o = i / 768, k = i % 768;
        bopo[i] = f2bf(k < 512 ? H[o * 512 + k] : sV[o * 256 + (k - 512)]); return; }
    i -= n2;
    if (i < n3) { G1[i] = f2bf(F[i]); return; }
    i -= n3;
    if (i < n3) { int r = i / 512, c = i % 512; Gt1[i] = f2bf(F[c * 512 + r]); }
}

// Copy rows of 512 (f32 or bf16 strided src) -> contiguous f32 + bf16 mirror.
__global__ void copy_rows_k(const void* src, int src_bf16,
                            long s_base, long s_os, long s_is, long s_ic,
                            float* dstf, unsigned short* dstm, long d_base, long n) {
    long i = (long)blockIdx.x * 256 + threadIdx.x;
    const long stride = (long)gridDim.x * 256;
    for (; i < n; i += stride) {
        const long r = i >> 9;
        const long kc = i & 511;
        const long so = s_base + (r / s_ic) * s_os + (r % s_ic) * s_is + kc;
        const float v = src_bf16 ? bf2f(((const unsigned short*)src)[so])
                                 : ((const float*)src)[so];
        dstf[d_base + i] = v;
        dstm[d_base + i] = f2bf(v);
    }
}

static GemmDesc D0() {
    GemmDesc d = {};
    d.a0_ic = 1; d.a1_ic = 1; d.c_ic = 1;
    d.zdiv = 1L << 40;
    d.ksplit = 1 << 30;
    d.b_ldb = 512; d.K = 512;
    return d;
}

extern "C" void kernel_launch(void* const* d_in, const int* in_sizes, int n_in,
                              void* d_out, int out_size, void* d_ws, size_t ws_size,
                              hipStream_t stream) {
    const float* st0 = (const float*)d_in[0];   // state   (64,512)
    const float* inp = (const float*)d_in[1];   // inputs  (64,1024,256)
    const float* Wn  = (const float*)d_in[2];   // W_noise (64,1024,512)
    const float* Vn  = (const float*)d_in[3];   // V_noise (64,1024,256)
    const float* F   = (const float*)d_in[4];   // F       (512,512)
    const float* Bm  = (const float*)d_in[5];   // B_mat   (512,256)
    const float* H   = (const float*)d_in[6];   // H       (256,512)
    const float* sW  = (const float*)d_in[7];   // sqrt_S_W(512,512)
    const float* sV  = (const float*)d_in[8];   // sqrt_S_V(256,256)

    float* states = (float*)d_out;              // (64,1024,512) f32
    float* obs    = states + 33554432L;         // (64,1024,256) f32

    const long MS = 262144;   // 512*512
    const long CB = 32768;    // 64*512 per-chunk carry block
    const int  NC = 128;      // chunks
    const int  CL = 8;        // chunk length
    const long TOS = 524288;  // batch stride (1024*512)
    const long COS = (long)CL * 512;   // chunk stride within batch row = 4096

    // ws layout
    unsigned short* Smir = (unsigned short*)d_ws;       // 33,554,432 bf16
    unsigned short* G    = Smir + 33554432L;            // G[j] = F^{j+1}, j=0..7
    unsigned short* Gt   = G + 8 * MS;                  // transposes
    unsigned short* Qb   = Gt + 8 * MS;                 // F^{16*2^j}, j=0..5
    unsigned short* Qtb  = Qb + 6 * MS;                 // transposes j=0..4
    unsigned short* BopD = Qtb + 5 * MS;                // 512*768
    unsigned short* BopO = BopD + 512 * 768;            // 256*768
    float* a0f = (float*)(BopO + 256 * 768);            // NC*CB f32 carries
    float* a1f = a0f + (long)NC * CB;
    unsigned short* a0m = (unsigned short*)(a1f + (long)NC * CB);
    unsigned short* a1m = a0m + (long)NC * CB;
    (void)ws_size; (void)in_sizes; (void)n_in; (void)out_size;

    auto L128 = [&](const GemmDesc& d, int gx, int gy, int gz) {
        gemm_k<128, 128><<<dim3(gx, gy, gz), dim3(256), 0, stream>>>(d);
    };
    auto L64 = [&](const GemmDesc& d, int gx, int gy, int gz) {
        gemm_k<64, 256><<<dim3(gx, gy, gz), dim3(256), 0, stream>>>(d);
    };

    // 1) operators + F, F^T
    build_ops_k<<<dim3(4352), dim3(256), 0, stream>>>(F, Bm, H, sW, sV, BopD, BopO, G, Gt);

    // 2) drive = [inputs | W_noise] @ BopD^T -> Smir (bf16)
    {
        GemmDesc d = D0();
        d.a0 = inp; d.a0_f32 = 1; d.a0_os = 256;
        d.a1 = Wn;  d.a1_f32 = 1; d.a1_os = 512;
        d.ksplit = 256; d.K = 768;
        d.b = BopD; d.b_ldb = 768;
        d.cm = Smir; d.c_os = 512;
        L128(d, 4, 512, 1);
    }

    // 3) phase 1: 7 sequential local-scan steps (M = 64*128 = 8192 rows each)
    for (int k = 1; k < CL; ++k) {
        GemmDesc d = D0();
        d.a0 = Smir; d.a0_base = (long)(k - 1) * 512;
        d.a0_ic = NC; d.a0_is = COS; d.a0_os = TOS;
        d.b = G;  // F
        d.c_base = (long)k * 512;
        d.c_ic = NC; d.c_is = COS; d.c_os = TOS;
        d.beta = 2;
        d.cm = Smir; d.cm_base = (long)k * 512;
        L128(d, 4, 64, 1);
    }

    // 4) powers: doubling G[1..7] (+T in-epilogue)
    for (int m = 1; m <= 4; m <<= 1) {
        GemmDesc d = D0();
        d.a0 = G; d.a0_os = 512; d.a_zr = MS;
        d.b = Gt; d.b_base = (long)(m - 1) * MS;
        d.cm = G;  d.cm_base  = (long)m * MS; d.c_os = 512; d.c_zr = MS;
        d.cmT = Gt; d.cmT_base = (long)m * MS;
        L128(d, 4, 4, m);
    }
    // Q chain: Qb[0]=F^16=F^8@F^8; Qb[j]=Qb[j-1]^2, j=1..5
    for (int j = 0; j <= 5; ++j) {
        GemmDesc d = D0();
        if (j == 0) { d.a0 = G;  d.a0_base = 7 * MS; d.b = Gt;  d.b_base = 7 * MS; }
        else        { d.a0 = Qb; d.a0_base = (j-1)*MS; d.b = Qtb; d.b_base = (j-1)*MS; }
        d.a0_os = 512;
        d.cm = Qb; d.cm_base = (long)j * MS; d.c_os = 512;
        if (j <= 4) { d.cmT = Qtb; d.cmT_base = (long)j * MS; }
        L128(d, 4, 4, 1);
    }

    // 5) carries a[0]=s0, a[c]=local[c-1, CL-1]
    copy_rows_k<<<dim3(128), dim3(256), 0, stream>>>(
        st0, 0, 0, 512, 0, 1, a0f, a0m, 0, CB);
    copy_rows_k<<<dim3(2048), dim3(256), 0, stream>>>(
        Smir, 1, (long)(CL - 1) * 512, COS, TOS, 64, a0f, a0m, CB, (long)(NC - 1) * CB);

    // 6) Kogge-Stone: nxt[c] = cur[c] (c<s, prefix copy) ;
    //                 nxt[c] = cur[c] + cur[c-s] @ (F^{CL*s})^T (c>=s)
    float* cur = a0f; unsigned short* curm = a0m;
    float* nxt = a1f; unsigned short* nxtm = a1m;
    for (int s = 1; s < NC; s <<= 1) {
        const long np = (long)s * CB;
        const int cg = (int)((np + 255) / 256) < 2048 ? (int)((np + 255) / 256) : 2048;
        copy_rows_k<<<dim3(cg), dim3(256), 0, stream>>>(
            cur, 0, 0, 512, 0, 1, nxt, nxtm, 0, np);
        GemmDesc d = D0();
        d.a0 = curm; d.a0_os = 512; d.a_zr = CB;
        if (s == 1) { d.b = G;  d.b_base = 7 * MS; }                       // F^8
        else        { d.b = Qb; d.b_base = (long)(__builtin_ctz(s) - 1) * MS; } // F^{8s}
        d.c = nxt; d.cbeta = cur; d.c_base = (long)s * CB;
        d.c_os = 512; d.c_zr = CB; d.beta = 1;
        d.cm = nxtm; d.cm_base = (long)s * CB;
        L64(d, 2, 1, NC - s);
        float* tf = cur; cur = nxt; nxt = tf;
        unsigned short* tm = curm; curm = nxtm; nxtm = tm;
    }

    // 7) phase 3: states[b, c*CL+k, :] = local + init_c @ (F^{k+1})^T ; z = c*CL+k
    {
        GemmDesc d = D0();
        d.a0 = curm; d.a0_os = 512; d.a_zq = CB; d.zdiv = CL;
        d.b = G; d.b_zr = MS;
        d.c = states; d.c_zq = COS; d.c_zr = 512; d.c_os = TOS;
        d.beta = 2;
        d.cm = Smir; d.cm_base = 0;
        L64(d, 2, 1, NC * CL);
    }

    // 8) obs = [states_bf16 | V_noise] @ BopO^T
    {
        GemmDesc d = D0();
        d.a0 = Smir; d.a0_os = 512;
        d.a1 = Vn; d.a1_f32 = 1; d.a1_os = 256;
        d.ksplit = 512; d.K = 768;
        d.b = BopO; d.b_ldb = 768;
        d.c = obs; d.c_os = 256;
        L128(d, 2, 512, 1);
    }
}